// Round 11
// baseline (1634.702 us; speedup 1.0000x reference)
//
#include <hip/hip_runtime.h>
#include <hip/hip_bf16.h>

// R11 = R10 + XCD-local CONTROL plane (flags on the R10-proven L2 path):
//  - local mode: flag store = volatile plain store (after __syncthreads
//    vmcnt-drain => ordered behind data); flag poll = per-iteration
//    {buffer_inv; vmcnt(0); volatile load} — the same mechanism R10 proved
//    correct for the v/h data plane (absmax bit-exact over 256 steps).
//  - h + flagB published BEFORE out[] HBM stores (out-store drain off the
//    inter-WG chain).
//  - fallback (census fails): byte-identical R6 agent transport.
#define T_STEPS 256
#define BATCH   128
#define DIN     512
#define DH      512
#define NGATE   2048
#define NCL     8
#define WPC     32
#define ROWS_CL 16
#define NWG     (NCL * WPC)

typedef __attribute__((ext_vector_type(8))) short short8;
typedef __attribute__((ext_vector_type(4))) float f32x4;
typedef unsigned long long u64;

#define OUT_HX ((size_t)T_STEPS * BATCH * DH)
#define OUT_CX (OUT_HX + (size_t)BATCH * DH)

// ---- ws layout (R10) ----
#define WB_OFF    0
#define XB_OFF    (4 * 1024 * 1024)
#define BT_OFF    (XB_OFF + 32 * 1024 * 1024)
#define CL_OFF    (BT_OFF + 8192)
#define CL_STRIDE (160 * 1024)
#define CLV_OFF   0                  // v: 16*2048*4 = 131072 B
#define CLH_OFF   131072             // h: 16*512*2  =  16384 B
#define CLF_OFF   147456             // slotA: 32 x 128 B = 4096 B
#define CLFB_OFF  (CLF_OFF + 4096)   // slotB: 16 x 128 B = 2048 B
#define SLOT_STRIDE 32               // ints per slot (128 B)
#define BOOT_OFF  (CL_OFF + NCL * CL_STRIDE)

#define LDS_W_BYTES 131072           // 64 cols x 1024 K x bf16, swizzled
#define LDS_TOTAL   (LDS_W_BYTES + 4 * DH * 4)

__device__ inline ushort f2bf(float x) {
  uint u = __float_as_uint(x);
  u += 0x7fffu + ((u >> 16) & 1u);
  return (ushort)(u >> 16);
}
__device__ inline float sigm(float x) { return 1.f / (1.f + __expf(-x)); }
__device__ inline float tanhf_(float x) { return 1.f - 2.f / (1.f + __expf(2.f * x)); }

// agent-scope ops (fallback transport + bootstrap) — R6-proven
__device__ inline u64 ald64(const u64* p) {
  return __hip_atomic_load(p, __ATOMIC_RELAXED, __HIP_MEMORY_SCOPE_AGENT);
}
__device__ inline void ast32(uint* p, uint v) {
  __hip_atomic_store(p, v, __ATOMIC_RELAXED, __HIP_MEMORY_SCOPE_AGENT);
}
__device__ inline int aldi(const int* p) {
  return __hip_atomic_load(p, __ATOMIC_RELAXED, __HIP_MEMORY_SCOPE_AGENT);
}
__device__ inline void asti(int* p, int v) {
  __hip_atomic_store(p, v, __ATOMIC_RELAXED, __HIP_MEMORY_SCOPE_AGENT);
}
// L1 invalidate: next plain loads refill from XCD L2 (R10-proven)
__device__ inline void l1inv() {
  asm volatile("buffer_inv" ::: "memory");
  asm volatile("s_waitcnt vmcnt(0)" ::: "memory");
}
// flag ops, transport-tiered
template<bool L> __device__ inline void fstore(int* p, int v) {
  if constexpr (L) *(volatile int*)p = v;
  else             asti(p, v);
}
template<bool L> __device__ inline int fload(const int* p) {
  if constexpr (L) return *(volatile const int*)p;
  else             return aldi(p);
}

union U16 { u64 q[2]; short8 s; };
union UF2 { u64 q; float f[2]; };

// -------- prep kernels --------
__global__ void k_prep_w(const float* __restrict__ Wf, const float* __restrict__ Wi,
                         const float* __restrict__ Wu, const float* __restrict__ Wo,
                         ushort* __restrict__ Wb) {
  size_t i4 = ((size_t)blockIdx.x * 256 + threadIdx.x) * 4;
  if (i4 >= (size_t)NGATE * 1024) return;
  int row = (int)(i4 >> 10);
  int col = (int)(i4 & 1023);
  const float* W = (row < 512) ? Wf : (row < 1024) ? Wi : (row < 1536) ? Wu : Wo;
  int r = row & 511;
  float4 w = *(const float4*)&W[(size_t)r * 1024 + col];
  ushort4 o = make_ushort4(f2bf(w.x), f2bf(w.y), f2bf(w.z), f2bf(w.w));
  *(ushort4*)&Wb[i4] = o;
}

__global__ void k_prep_x(const float* __restrict__ X, ushort* __restrict__ Xb) {
  size_t i4 = ((size_t)blockIdx.x * 256 + threadIdx.x) * 4;
  if (i4 >= (size_t)T_STEPS * BATCH * DIN) return;
  float4 xv = *(const float4*)&X[i4];
  ushort4 o = make_ushort4(f2bf(xv.x), f2bf(xv.y), f2bf(xv.z), f2bf(xv.w));
  *(ushort4*)&Xb[i4] = o;
}

__global__ void k_prep_misc(const float* __restrict__ bf_, const float* __restrict__ tf_,
                            const float* __restrict__ bi_, const float* __restrict__ ti_,
                            const float* __restrict__ bu_, const float* __restrict__ tu_,
                            const float* __restrict__ bo_, const float* __restrict__ to_,
                            float* __restrict__ bt, char* __restrict__ clbase,
                            int* __restrict__ boot) {
  int idx = blockIdx.x * 256 + threadIdx.x;
  if (idx < NGATE) {
    int g = idx >> 9, k = idx & 511;
    const float* b = (g == 0) ? bf_ : (g == 1) ? bi_ : (g == 2) ? bu_ : bo_;
    const float* t = (g == 0) ? tf_ : (g == 1) ? ti_ : (g == 2) ? tu_ : to_;
    bt[idx] = b[k] + t[k];
  }
  if (idx < NCL * 4096) {  // zero h (16*512 bf16 = 4096 uints per cluster)
    int c = idx >> 12, w = idx & 4095;
    ((uint*)(clbase + (size_t)c * CL_STRIDE + CLH_OFF))[w] = 0u;
  }
  if (idx < NCL * 2048) {  // zero flag region (8 KB per cluster)
    int c = idx >> 11, w = idx & 2047;
    ((int*)(clbase + (size_t)c * CL_STRIDE + CLF_OFF))[w] = 0;
  }
  if (idx < 16) boot[idx] = 0;
}

// -------- main loop body (L = XCD-local data+control plane) --------
template<bool L>
__device__ __forceinline__ void run_main(
    const ushort* __restrict__ Xb, const ushort* __restrict__ Wb,
    const float* __restrict__ bt, char* cl, float* __restrict__ out,
    int cluster, int mem, ushort* wlds, float* lds_g) {
  const int tid  = threadIdx.x;
  const int lane = tid & 63;
  const int wave = tid >> 6;

  float*  v_cl  = (float*)(cl + CLV_OFF);
  u64*    h_cl  = (u64*)(cl + CLH_OFF);
  uint*   h_cl32= (uint*)(cl + CLH_OFF);
  int*    slotA = (int*)(cl + CLF_OFF);
  int*    slotB = (int*)(cl + CLFB_OFF);

  const int nb    = mem * 64 + wave * 16;
  const int ar    = lane & 15;
  const int kx    = (lane >> 4) << 3;      // ushort units
  const int crow0 = cluster * ROWS_CL;
  const int row   = crow0 + mem;
  const int wrow  = wave * 16 + ar;

  // ---- stage W slice into LDS (XOR-swizzled rows) ----
  {
    const char* wsrc = (const char*)(Wb + (size_t)(mem * 64) * 1024);
#pragma unroll
    for (int it = 0; it < 32; ++it) {
      int idx16 = it * 256 + tid;
      int r  = idx16 >> 7;
      int kb = (idx16 & 127) << 4;
      short8 w = *(const short8*)(wsrc + (size_t)r * 2048 + kb);
      *(short8*)((char*)wlds + (size_t)r * 2048 + (kb ^ ((r & 7) << 4))) = w;
    }
  }
#define WFRAG(KT) (*(const short8*)((const char*)wlds + (size_t)wrow * 2048 + \
                    ((((KT) * 64) + (kx << 1)) ^ ((ar & 7) << 4))))

  float btr[8];
  {
    const int e0 = lane << 3;
#pragma unroll
    for (int j = 0; j < 8; ++j) btr[j] = bt[wave * DH + e0 + j];
  }
  __syncthreads();

  float c0 = 0.f, c1 = 0.f;
  f32x4 accE = {0.f, 0.f, 0.f, 0.f}, accO = {0.f, 0.f, 0.f, 0.f};

#define XPART(TT) do {                                                        \
    accE = (f32x4){0.f, 0.f, 0.f, 0.f};                                       \
    accO = (f32x4){0.f, 0.f, 0.f, 0.f};                                       \
    const ushort* Ax = Xb + ((size_t)(TT) * BATCH + crow0 + ar) * DIN + kx;   \
    _Pragma("unroll")                                                         \
    for (int kt = 0; kt < 16; kt += 2) {                                      \
      short8 a0 = *(const short8*)(Ax + kt * 32);                             \
      short8 a1 = *(const short8*)(Ax + (kt + 1) * 32);                       \
      accE = __builtin_amdgcn_mfma_f32_16x16x32_bf16(a0, WFRAG(kt), accE, 0, 0, 0);     \
      accO = __builtin_amdgcn_mfma_f32_16x16x32_bf16(a1, WFRAG(kt + 1), accO, 0, 0, 0); \
    }                                                                         \
  } while (0)

  XPART(0);

  for (int t = 0; t < T_STEPS; ++t) {
    const int ep = t + 1;
    // ---- h-part GEMM: A = h (L: plain/L2; else agent) ----
    {
      U16 af[16];
#pragma unroll
      for (int kt = 0; kt < 16; ++kt) {
        const u64* p = h_cl + (((size_t)ar * DH + kt * 32 + kx) >> 2);
        if constexpr (L) { af[kt].q[0] = p[0];       af[kt].q[1] = p[1]; }
        else             { af[kt].q[0] = ald64(p);   af[kt].q[1] = ald64(p + 1); }
      }
#pragma unroll
      for (int kt = 0; kt < 16; kt += 2) {
        accE = __builtin_amdgcn_mfma_f32_16x16x32_bf16(af[kt].s,     WFRAG(16 + kt),     accE, 0, 0, 0);
        accO = __builtin_amdgcn_mfma_f32_16x16x32_bf16(af[kt + 1].s, WFRAG(16 + kt + 1), accO, 0, 0, 0);
      }
    }
    // ---- v slice publish ----
    {
      const int rbase = (lane >> 4) << 2;
      float* vp = v_cl + (size_t)rbase * NGATE + nb + ar;
#pragma unroll
      for (int r = 0; r < 4; ++r) {
        float val = accE[r] + accO[r];
        if constexpr (L) vp[(size_t)r * NGATE] = val;
        else             ast32((uint*)&vp[(size_t)r * NGATE], __float_as_uint(val));
      }
    }
    __syncthreads();   // vmcnt drain: v stores ack'd (L: in XCD L2)
    if (tid == 0) fstore<L>(&slotA[mem * SLOT_STRIDE], ep);

    if (mem < ROWS_CL) {
      // ---- wait all 32 v flags (narrow poll; L: L2 via per-iter inv) ----
      if (wave == 0) {
        for (;;) {
          if constexpr (L) l1inv();
          int s = (lane < WPC) ? fload<L>(&slotA[lane * SLOT_STRIDE]) : ep;
          if (__all(s >= ep)) break;
          __builtin_amdgcn_s_sleep(1);
        }
        if constexpr (L) l1inv();   // wipe any line filled mid-poll
      }
      __syncthreads();
      asm volatile("" ::: "memory");
      // ---- scan row `mem`: wave = gate ----
      {
        const int g  = wave;
        const int e0 = lane << 3;
        const u64* vr = (const u64*)(v_cl + (size_t)mem * NGATE + g * DH + e0);
        UF2 w0, w1, w2, w3;
        if constexpr (L) { w0.q = vr[0]; w1.q = vr[1]; w2.q = vr[2]; w3.q = vr[3]; }
        else { w0.q = ald64(vr); w1.q = ald64(vr + 1); w2.q = ald64(vr + 2); w3.q = ald64(vr + 3); }
        float p0 = __cosf(w0.f[0] + btr[0]);
        float p1 = __cosf(w0.f[1] + btr[1]);
        float p2 = __cosf(w1.f[0] + btr[2]);
        float p3 = __cosf(w1.f[1] + btr[3]);
        float p4 = __cosf(w2.f[0] + btr[4]);
        float p5 = __cosf(w2.f[1] + btr[5]);
        float p6 = __cosf(w3.f[0] + btr[6]);
        float p7 = __cosf(w3.f[1] + btr[7]);
        float q0 = p0, q1 = q0 * p1, q2 = q1 * p2, q3 = q2 * p3;
        float q4 = q3 * p4, q5 = q4 * p5, q6 = q5 * p6, q7 = q6 * p7;
        float a = q7;
#pragma unroll
        for (int off = 1; off < 64; off <<= 1) {
          float o = __shfl_up(a, off);
          a = (lane >= off) ? a * o : a;
        }
        float ex = __shfl_up(a, 1);
        ex = (lane == 0) ? 1.f : ex;
        float G0 = ex * q0, G1 = ex * q1, G2 = ex * q2, G3 = ex * q3;
        float G4 = ex * q4, G5 = ex * q5, G6 = ex * q6, G7 = ex * q7;
        float4 r0, r1;
        if (g == 2) {
          r0 = make_float4(tanhf_(G0), tanhf_(G1), tanhf_(G2), tanhf_(G3));
          r1 = make_float4(tanhf_(G4), tanhf_(G5), tanhf_(G6), tanhf_(G7));
        } else {
          r0 = make_float4(sigm(G0), sigm(G1), sigm(G2), sigm(G3));
          r1 = make_float4(sigm(G4), sigm(G5), sigm(G6), sigm(G7));
        }
        *(float4*)&lds_g[g * DH + e0]     = r0;
        *(float4*)&lds_g[g * DH + e0 + 4] = r1;
      }
      __syncthreads();
      {
        const int k = tid << 1;
        float f0 = lds_g[0 * DH + k], f1 = lds_g[0 * DH + k + 1];
        float i0 = lds_g[1 * DH + k], i1 = lds_g[1 * DH + k + 1];
        float u0 = lds_g[2 * DH + k], u1 = lds_g[2 * DH + k + 1];
        float o0 = lds_g[3 * DH + k], o1 = lds_g[3 * DH + k + 1];
        c0 = f0 * c0 + i0 * u0;
        c1 = f1 * c1 + i1 * u1;
        float h0 = o0 * tanhf_(c0);
        float h1 = o1 * tanhf_(c1);
        // ---- h publish FIRST (critical path), then flagB, then out[] ----
        uint hbits = ((uint)f2bf(h1) << 16) | (uint)f2bf(h0);
        if constexpr (L) h_cl32[mem * 256 + tid] = hbits;
        else             ast32(&h_cl32[mem * 256 + tid], hbits);
        __syncthreads();   // drain h stores (L: L2-ack)
        if (tid == 0) fstore<L>(&slotB[mem * SLOT_STRIDE], ep);
        float2 hp = make_float2(h0, h1);
        *(float2*)&out[((size_t)t * BATCH + row) * DH + k] = hp;
        if (t == T_STEPS - 1) {
          *(float2*)&out[OUT_HX + (size_t)row * DH + k] = hp;
          float2 cp = make_float2(c0, c1);
          *(float2*)&out[OUT_CX + (size_t)row * DH + k] = cp;
        }
      }
      __syncthreads();   // lds_g WAR protection
    }

    if (t + 1 < T_STEPS) {
      // ---- overlapped x-part of t+1 (needs no h) ----
      XPART(t + 1);
      // ---- wait all 16 h flags ----
      if (wave == 0) {
        for (;;) {
          if constexpr (L) l1inv();
          int s = (lane < ROWS_CL) ? fload<L>(&slotB[lane * SLOT_STRIDE]) : ep;
          if (__all(s >= ep)) break;
          __builtin_amdgcn_s_sleep(1);
        }
        if constexpr (L) l1inv();
      }
      __syncthreads();
      asm volatile("" ::: "memory");
    }
  }
#undef XPART
#undef WFRAG
}

// -------- persistent main kernel --------
__global__ __launch_bounds__(256, 1) void qlstm_main(
    const ushort* __restrict__ Xb, const ushort* __restrict__ Wb,
    const float* __restrict__ bt, char* __restrict__ clbase,
    int* __restrict__ boot, float* __restrict__ out) {
  extern __shared__ char smem[];
  ushort* wlds  = (ushort*)smem;
  float*  lds_g = (float*)(smem + LDS_W_BYTES);

  __shared__ int shboot[4];
  const int tid = threadIdx.x;

  // ---- bootstrap: XCD census via proven agent atomics (one-time) ----
  if (tid == 0) {
    uint xcc;
    asm volatile("s_getreg_b32 %0, hwreg(HW_REG_XCC_ID)" : "=s"(xcc));
    xcc &= 7;
    int slot = __hip_atomic_fetch_add(&boot[xcc], 1, __ATOMIC_RELAXED, __HIP_MEMORY_SCOPE_AGENT);
    __hip_atomic_fetch_add(&boot[8], 1, __ATOMIC_RELAXED, __HIP_MEMORY_SCOPE_AGENT);
    while (__hip_atomic_load(&boot[8], __ATOMIC_RELAXED, __HIP_MEMORY_SCOPE_AGENT) < NWG)
      __builtin_amdgcn_s_sleep(8);
    int ok = 1;
#pragma unroll
    for (int c2 = 0; c2 < NCL; ++c2)
      ok &= (__hip_atomic_load(&boot[c2], __ATOMIC_RELAXED, __HIP_MEMORY_SCOPE_AGENT) == WPC);
    shboot[0] = (int)xcc;
    shboot[1] = slot;
    shboot[2] = ok;
  }
  __syncthreads();
  const int local_ok = shboot[2];
  const int cluster  = local_ok ? shboot[0] : ((int)blockIdx.x & 7);
  const int mem      = local_ok ? shboot[1] : ((int)blockIdx.x >> 3);
  char* cl = clbase + (size_t)cluster * CL_STRIDE;

  if (local_ok)
    run_main<true>(Xb, Wb, bt, cl, out, cluster, mem, wlds, lds_g);
  else
    run_main<false>(Xb, Wb, bt, cl, out, cluster, mem, wlds, lds_g);
}

extern "C" void kernel_launch(void* const* d_in, const int* in_sizes, int n_in,
                              void* d_out, int out_size, void* d_ws, size_t ws_size,
                              hipStream_t stream) {
  const float* X  = (const float*)d_in[0];
  const float* Wf = (const float*)d_in[1];
  const float* bf = (const float*)d_in[2];
  const float* tf = (const float*)d_in[3];
  const float* Wi = (const float*)d_in[4];
  const float* bi = (const float*)d_in[5];
  const float* ti = (const float*)d_in[6];
  const float* Wu = (const float*)d_in[7];
  const float* bu = (const float*)d_in[8];
  const float* tu = (const float*)d_in[9];
  const float* Wo = (const float*)d_in[10];
  const float* bo = (const float*)d_in[11];
  const float* to = (const float*)d_in[12];

  char* ws = (char*)d_ws;
  ushort* Wb     = (ushort*)(ws + WB_OFF);
  ushort* Xb     = (ushort*)(ws + XB_OFF);
  float*  bt     = (float*)(ws + BT_OFF);
  char*   clbase = ws + CL_OFF;
  int*    boot   = (int*)(ws + BOOT_OFF);
  float*  out    = (float*)d_out;

  static bool attr_set = false;
  if (!attr_set) {
    hipFuncSetAttribute((const void*)qlstm_main,
                        hipFuncAttributeMaxDynamicSharedMemorySize, LDS_TOTAL);
    attr_set = true;
  }

  k_prep_w<<<dim3((NGATE * 1024 / 4 + 255) / 256), dim3(256), 0, stream>>>(Wf, Wi, Wu, Wo, Wb);
  k_prep_x<<<dim3((T_STEPS * BATCH * DIN / 4 + 255) / 256), dim3(256), 0, stream>>>(X, Xb);
  k_prep_misc<<<dim3(256), dim3(256), 0, stream>>>(bf, tf, bi, ti, bu, tu, bo, to, bt, clbase, boot);
  qlstm_main<<<dim3(NWG), dim3(256), LDS_TOTAL, stream>>>(Xb, Wb, bt, clbase, boot, out);
}